// Round 17
// baseline (286.030 us; speedup 1.0000x reference)
//
#include <hip/hip_runtime.h>
#include <hip/hip_fp16.h>

// MRI adjoint: masked centered 2D IFFT per (coil,frame) -> conj(smaps) combine
// -> bilinear warp-adjoint scatter -> sum over frames. Nx=Ny=320, Nc=16, Nt=25.
//
// FFT: 320 = 5*64; one wave per transform. Selection-free butterfly
// z = cmul(o + sgn*z, w) with lane-resident twiddles; radix-5 twiddles folded
// into the (identity-twiddle) m=1 stage. Cross-lane: m=1,2 DPP quad_perm,
// m=4,8,16 immediate ds_swizzle, m=32 shfl_xor.
// Centered-transform signs folded into pass1 output & pre-signed smaps.
// tmp fp16 half2 [c][t][ky][nx]; smaps/im_aux fp16.
// prep (round-17): SPLIT into 4 kernels for per-phase rocprof attribution
// (rounds 11-16: six mask-phase variants all ~88-100us on the merged kernel;
// counters couldn't attribute). Mask kernel = round-14 y-major float4
// structure + 2-deep strip double-buffer (breaks the load->pack->load serial
// chain from strip-buffer reuse). out_f zero via hipMemsetAsync.
// Scatter: LDS __half2 accumulator + ds_pk_add_f16 taps (LDS atomics are
// ~lane-serialized; halving lane-atomics was round-10's win).

#define NX 320
#define NT 25
#define NC 16
#define BR 32
#define WH 16
static const float INV320 = 1.0f / 320.0f;

typedef float v2f __attribute__((ext_vector_type(2)));

__device__ __forceinline__ int rev6(int l) {
  return ((l & 1) << 5) | ((l & 2) << 3) | ((l & 4) << 1) |
         ((l & 8) >> 1) | ((l & 16) >> 3) | ((l & 32) >> 5);
}

// Lane-resident twiddle state. Stages st=0..4 (m=32..2): sg=bot?-1:+1,
// (cst,sst)=bot?(c,s):(1,0). Stage m=1: sg5 plus folded radix-5 twiddles.
struct Tw {
  float cst[5], sst[5], sg[5];
  float sg5;
  float c5[5], s5[5];
};

__device__ __forceinline__ void make_tw(int lane, Tw& tw) {
#pragma unroll
  for (int st = 0; st < 5; ++st) {
    int m = 32 >> st;
    bool bot = (lane & m) != 0;
    int j = lane & (m - 1);
    float ang = 3.14159265358979323846f * (float)j / (float)m;
    float s, c;
    __sincosf(ang, &s, &c);
    tw.sg[st] = bot ? -1.f : 1.f;
    tw.cst[st] = bot ? c : 1.f;
    tw.sst[st] = bot ? s : 0.f;
  }
  tw.sg5 = (lane & 1) ? -1.f : 1.f;
  int k1 = rev6(lane);
  float b = (6.283185307179586f / 320.0f) * (float)k1;
  float s1, c1;
  __sincosf(b, &s1, &c1);
  tw.c5[0] = 1.f;
  tw.s5[0] = 0.f;
  tw.c5[1] = c1;
  tw.s5[1] = s1;
  tw.c5[2] = c1 * c1 - s1 * s1;
  tw.s5[2] = 2.f * c1 * s1;
  tw.c5[3] = tw.c5[2] * c1 - tw.s5[2] * s1;
  tw.s5[3] = tw.c5[2] * s1 + tw.s5[2] * c1;
  tw.c5[4] = tw.c5[2] * tw.c5[2] - tw.s5[2] * tw.s5[2];
  tw.s5[4] = 2.f * tw.c5[2] * tw.s5[2];
}

// Cross-lane xor exchange. m=1,2: DPP quad_perm (VALU pipe). m=4,8,16:
// immediate ds_swizzle. m=32: shfl_xor (ds_bpermute).
template <int M>
__device__ __forceinline__ float lxor(float x) {
  if constexpr (M == 1) {
    return __int_as_float(
        __builtin_amdgcn_mov_dpp(__float_as_int(x), 0xB1, 0xF, 0xF, true));
  } else if constexpr (M == 2) {
    return __int_as_float(
        __builtin_amdgcn_mov_dpp(__float_as_int(x), 0x4E, 0xF, 0xF, true));
  } else if constexpr (M == 32) {
    return __shfl_xor(x, 32);
  } else {
    constexpr int pat = (M << 10) | 0x1F;  // BitMode: xor=M, and=0x1F
    return __int_as_float(__builtin_amdgcn_ds_swizzle(__float_as_int(x), pat));
  }
}

// (z.x + i z.y) * (c + i s)
__device__ __forceinline__ v2f cmul(v2f z, float c, float s) {
  v2f sw = {-z.y, z.x};
  return c * z + s * sw;
}

template <int M>
__device__ __forceinline__ void bstage(v2f z[5], float sg, float c, float s) {
#pragma unroll
  for (int q = 0; q < 5; ++q) {
    v2f o;
    o.x = lxor<M>(z[q].x);
    o.y = lxor<M>(z[q].y);
    v2f t = o + sg * z[q];
    z[q] = cmul(t, c, s);  // top lanes: (c,s)=(1,0) -> identity
  }
}

// Unnormalized inverse 320-pt DFT: lane l enters with x[5l+q] in z[q];
// exits with X[rev6(l) + 64*q].
__device__ __forceinline__ void fft320p(v2f z[5], const Tw& tw) {
  bstage<32>(z, tw.sg[0], tw.cst[0], tw.sst[0]);
  bstage<16>(z, tw.sg[1], tw.cst[1], tw.sst[1]);
  bstage<8>(z, tw.sg[2], tw.cst[2], tw.sst[2]);
  bstage<4>(z, tw.sg[3], tw.cst[3], tw.sst[3]);
  bstage<2>(z, tw.sg[4], tw.cst[4], tw.sst[4]);
  {
    v2f o;
    o.x = lxor<1>(z[0].x);
    o.y = lxor<1>(z[0].y);
    z[0] = o + tw.sg5 * z[0];  // c5[0]=1: no cmul
#pragma unroll
    for (int q = 1; q < 5; ++q) {
      o.x = lxor<1>(z[q].x);
      o.y = lxor<1>(z[q].y);
      v2f t = o + tw.sg5 * z[q];
      z[q] = cmul(t, tw.c5[q], tw.s5[q]);
    }
  }
  v2f t0 = z[0], t1 = z[1], t2 = z[2], t3 = z[3], t4 = z[4];
  const float C1 = 0.30901699437494742f, S1 = 0.95105651629515357f;
  const float C2 = -0.80901699437494742f, S2 = 0.58778525229247312f;
  v2f a1 = t1 + t4, b1 = t1 - t4;
  v2f a2 = t2 + t3, b2 = t2 - t3;
  z[0] = t0 + a1 + a2;
  v2f p = t0 + C1 * a1 + C2 * a2;
  v2f q_ = S1 * b1 + S2 * b2;
  v2f r = t0 + C2 * a1 + C1 * a2;
  v2f u = S2 * b1 - S1 * b2;
  v2f qi = {-q_.y, q_.x};
  v2f ui = {-u.y, u.x};
  z[1] = p + qi;
  z[4] = p - qi;
  z[2] = r + ui;
  z[3] = r - ui;
}

// mask [x][y][c][t] -> bit-packed mp[c][y][x]. Block = (xt, y), y-major
// (consecutive bids read adjacent 1600B chunks). Per-wave strip loads are
// float4 double-buffered: strip k+1's loads issue before strip k's pack.
__global__ __launch_bounds__(256) void prep_mask_k(
    const float* __restrict__ mask, unsigned int* __restrict__ mp) {
  __shared__ float4 stage4[4][2][100];    // 12.8 KB: [wave][slot][float4]
  __shared__ unsigned int tileu[16][17];  // 1.1 KB
  int bid = blockIdx.x, tid = threadIdx.x;
  int xt = bid / 320, y = bid % 320;
  int w = tid >> 6, lane = tid & 63;
  const float4* src0 = (const float4*)(
      mask + ((size_t)((xt * 16 + w * 4) * NX) + y) * (NC * NT));
  const size_t s4str = (size_t)NX * (NC * NT) / 4;  // x-stride in float4
  if (lane < 50) {
    stage4[w][0][lane] = src0[lane];
    stage4[w][0][lane + 50] = src0[lane + 50];
  }
#pragma unroll
  for (int k = 0; k < 4; ++k) {
    if (k + 1 < 4) {  // prefetch next strip into the other slot
      const float4* s = src0 + (size_t)(k + 1) * s4str;
      if (lane < 50) {
        stage4[w][(k + 1) & 1][lane] = s[lane];
        stage4[w][(k + 1) & 1][lane + 50] = s[lane + 50];
      }
    }
    if (lane < 16) {
      const float* row = (const float*)&stage4[w][k & 1][0] + lane * 25;
      unsigned int bits = 0;
#pragma unroll
      for (int t = 0; t < NT; ++t) bits |= (row[t] != 0.f) ? (1u << t) : 0u;
      tileu[w * 4 + k][lane] = bits;
    }
  }
  __syncthreads();
  int c2 = tid >> 4, xx2 = tid & 15;
  mp[((size_t)(c2 * NX + y)) * NX + xt * 16 + xx2] = tileu[xx2][c2];
}

// kspace [x][y][c] -> kT[c][y][x] float2
__global__ __launch_bounds__(256) void prep_kspace_k(
    const float* __restrict__ kr, const float* __restrict__ ki,
    float2* __restrict__ kT) {
  __shared__ float2 tilef[16][17];
  int r = blockIdx.x, tid = threadIdx.x;
  int xt = r % 20, y = r / 20;
  int xx = tid >> 4, c = tid & 15;
  size_t si_ = (size_t)((xt * 16 + xx) * NX + y) * NC + c;
  tilef[xx][c] = make_float2(kr[si_], ki[si_]);
  __syncthreads();
  int c2 = tid >> 4, xx2 = tid & 15;
  kT[((size_t)(c2 * NX + y)) * NX + xt * 16 + xx2] = tilef[xx2][c2];
}

// smaps [x][y][c] -> sT[c][x][y] half2, pre-signed by (-1)^y
__global__ __launch_bounds__(256) void prep_smaps_k(
    const float* __restrict__ sr, const float* __restrict__ si,
    __half2* __restrict__ sT) {
  __shared__ float2 tiles[16][17];
  int r = blockIdx.x, tid = threadIdx.x;
  int yt = r % 20, x = r / 20;
  int yy = tid >> 4, c = tid & 15;
  size_t si_ = (size_t)(x * NX + yt * 16 + yy) * NC + c;
  tiles[yy][c] = make_float2(sr[si_], si[si_]);
  __syncthreads();
  int c2 = tid >> 4, yy2 = tid & 15;
  float2 v = tiles[yy2][c2];
  float sg = (yy2 & 1) ? -1.f : 1.f;  // (-1)^ny pre-sign
  sT[((size_t)(c2 * NX + x)) * NX + yt * 16 + yy2] =
      __floats2half2_rn(v.x * sg, v.y * sg);
}

// flow [nx][ny][2][t] -> fs[t][nx][ny] float2 (float2 loads)
__global__ __launch_bounds__(256) void prep_flow_k(
    const float* __restrict__ fl, float2* __restrict__ fs) {
  __shared__ float buf[1600];
  int r = blockIdx.x, tid = threadIdx.x;
  int nyt = r % 10, nx = r / 10;
  size_t base = (size_t)(nx * NX + nyt * 32) * (2 * NT);
  const float2* src2 = (const float2*)(fl + base);  // 8B-aligned
  float2* buf2 = (float2*)buf;
  for (int f = tid; f < 800; f += 256) buf2[f] = src2[f];
  __syncthreads();
  for (int f = tid; f < 1600; f += 256) {
    int t = f / 64;
    int k = f % 64;
    int nyl = k >> 1, d = k & 1;
    size_t di = ((size_t)(t * NX + nx) * NX + nyt * 32 + nyl) * 2 + d;
    ((float*)fs)[di] = buf[(nyl * 2 + d) * NT + t];
  }
}

// Pass 1: x-axis IFFT for coil chunk [c0, c0+G). Writes tmp[cg][t][ky][nx]
// fp16, pre-signed by (-1)^nx * (-1)^ky.
__global__ __launch_bounds__(256) void pass1_k(
    const float2* __restrict__ kT, const unsigned int* __restrict__ mp,
    __half2* __restrict__ tmp, int c0) {
  int y = blockIdx.x, cg = blockIdx.y, c = c0 + cg;
  int tid = threadIdx.x, lane = tid & 63, w = tid >> 6;
  v2f v[5];
  unsigned int mb[5];
  size_t rowbase = ((size_t)c * NX + y) * NX;
#pragma unroll
  for (int q = 0; q < 5; ++q) {
    int x = 5 * lane + q;
    float2 kv = kT[rowbase + x];
    float sg = ((lane + q) & 1) ? -INV320 : INV320;  // (-1)^x / 320
    v[q].x = kv.x * sg;
    v[q].y = kv.y * sg;
    mb[q] = mp[rowbase + x];
  }
  Tw tw;
  make_tw(lane, tw);
  int r6 = rev6(lane);
  float osg = ((lane & 32) ? -1.f : 1.f) * ((y & 1) ? -1.f : 1.f);
  for (int t = w; t < NT; t += 4) {
    v2f z[5];
#pragma unroll
    for (int q = 0; q < 5; ++q) {
      float m = ((mb[q] >> t) & 1u) ? 1.f : 0.f;
      z[q] = v[q] * m;
    }
    fft320p(z, tw);
    __half2* dst = tmp + ((size_t)(cg * NT + t) * NX + y) * NX;
#pragma unroll
    for (int k2 = 0; k2 < 5; ++k2)
      dst[r6 + 64 * k2] = __floats2half2_rn(z[k2].x * osg, z[k2].y * osg);
  }
}

// Pass 2: y-axis IFFT + conj(smaps) combine -> im_aux[t][nx][ny] fp16.
// 256 threads = 4 waves; block = (nx-tile of 4, t); wave j owns nx.
__global__ __launch_bounds__(256) void pass2_k(
    const __half2* __restrict__ tmp, const __half2* __restrict__ sT,
    __half2* __restrict__ im_aux, int c0, int G, int first) {
  int bx = blockIdx.x, t = blockIdx.y;
  int nxt_ = (bx >> 3) + 10 * (bx & 7);  // bijective on [0,80)
  int tid = threadIdx.x, lane = tid & 63, j = tid >> 6;
  int nx = nxt_ * 4 + j;
  int k1 = rev6(lane);
  Tw tw;
  make_tw(lane, tw);
  __shared__ __half2 tile[2][NX][5];  // 12.8 KB
  v2f acc[5] = {{0, 0}, {0, 0}, {0, 0}, {0, 0}, {0, 0}};

  int off[5], lw[5];
#pragma unroll
  for (int q = 0; q < 5; ++q) {
    int f = tid + q * 256;
    off[q] = (f >> 2) * NX + (f & 3);
    lw[q] = (f >> 2) * 5 + (f & 3);
  }
  const size_t pstride = (size_t)NT * NX * NX;
  const __half2* sbase = tmp + (size_t)t * NX * NX + nxt_ * 4;
  __half2* lds = &tile[0][0][0];

  __half2 nb[5];
#pragma unroll
  for (int q = 0; q < 5; ++q) nb[q] = sbase[off[q]];

  for (int cg = 0; cg < G; ++cg) {
    __half2 cb[5];
#pragma unroll
    for (int q = 0; q < 5; ++q) cb[q] = nb[q];
    if (cg + 1 < G) {
      const __half2* s = sbase + (size_t)(cg + 1) * pstride;
#pragma unroll
      for (int q = 0; q < 5; ++q) nb[q] = s[off[q]];  // in flight across iter
    }
    __half2* buf = lds + (cg & 1) * (NX * 5);
#pragma unroll
    for (int q = 0; q < 5; ++q) buf[lw[q]] = cb[q];
    const __half2* srow = sT + ((size_t)(c0 + cg) * NX + nx) * NX;
    __half2 smh[5];
#pragma unroll
    for (int k2 = 0; k2 < 5; ++k2) smh[k2] = srow[k1 + 64 * k2];
    __syncthreads();
    v2f z[5];
#pragma unroll
    for (int q = 0; q < 5; ++q) {
      float2 v = __half22float2(buf[(5 * lane + q) * 5 + j]);
      z[q].x = v.x;  // signs pre-folded in pass1
      z[q].y = v.y;
    }
    fft320p(z, tw);
#pragma unroll
    for (int k2 = 0; k2 < 5; ++k2) {
      float2 sm = __half22float2(smh[k2]);
      v2f zc = {z[k2].y, -z[k2].x};  // conj-MAC helper
      acc[k2] += sm.x * z[k2] + sm.y * zc;
    }
  }
  __half2* dst = im_aux + ((size_t)t * NX + nx) * NX;
#pragma unroll
  for (int k2 = 0; k2 < 5; ++k2) {
    int ny = k1 + 64 * k2;
    v2f nv = acc[k2];  // (-1)^ny folded into sT
    if (!first) {
      float2 old = __half22float2(dst[ny]);
      nv.x += old.x;
      nv.y += old.y;
    }
    dst[ny] = __floats2half2_rn(nv.x, nv.y);
  }
}

// Scatter: block (band b, seg, frame t). LDS-privatized 32-row band of
// __half2 (re,im) cells; taps via ds_pk_add_f16 (4 lane-atomics/element).
__global__ __launch_bounds__(1024) void scatter_k(
    const __half2* __restrict__ im, const float2* __restrict__ fs,
    __half2* __restrict__ out_p, float* __restrict__ out_f, int nseg) {
  int b = blockIdx.x, seg = blockIdx.y, t = blockIdx.z;
  int r0 = b * BR;
  int tid = threadIdx.x, lane = tid & 63, w = tid >> 6;
  __shared__ __half2 acc[BR * NX];  // 40 KB
  const __half2 h2z = __floats2half2_rn(0.f, 0.f);
  for (int i = tid; i < BR * NX; i += 1024) acc[i] = h2z;
  __syncthreads();
  int lo = max(r0 - WH, 0), hi = min(r0 + BR + WH, NX);
  int stride = 16 * nseg;
  for (int nx = lo + seg * 16 + w; nx < hi; nx += stride) {
    bool own = (nx >= r0) && (nx < r0 + BR);
    const __half2* imrow = im + ((size_t)t * NX + nx) * NX;
    const float2* frow = fs + ((size_t)t * NX + nx) * NX;
#pragma unroll
    for (int q = 0; q < 5; ++q) {
      int ny = lane + 64 * q;
      float2 v = __half22float2(imrow[ny]);
      float2 fl = frow[ny];
      float px = fminf(fmaxf((float)nx + fl.x, 0.f), 319.f);
      float py = fminf(fmaxf((float)ny + fl.y, 0.f), 319.f);
      int x0 = (int)floorf(px), y0 = (int)floorf(py);
      int x1 = min(x0 + 1, NX - 1), y1 = min(y0 + 1, NX - 1);
      float wx = px - (float)x0, wy = py - (float)y0;
      float w00 = (1.f - wx) * (1.f - wy), w01 = (1.f - wx) * wy;
      float w10 = wx * (1.f - wy), w11 = wx * wy;
#pragma unroll
      for (int half = 0; half < 2; ++half) {
        int r = half ? x1 : x0;
        float wa = half ? w10 : w00;
        float wb = half ? w11 : w01;
        if (r >= r0 && r < r0 + BR) {
          unsafeAtomicAdd(&acc[(r - r0) * NX + y0],
                          __floats2half2_rn(wa * v.x, wa * v.y));
          unsafeAtomicAdd(&acc[(r - r0) * NX + y1],
                          __floats2half2_rn(wb * v.x, wb * v.y));
        } else if (own) {
          int rb = (r / BR) * BR;
          if (nx < rb - WH || nx >= rb + BR + WH) {  // no band reads nx
            unsafeAtomicAdd(&out_f[((size_t)r * NX + y0) * 2], wa * v.x);
            unsafeAtomicAdd(&out_f[((size_t)r * NX + y0) * 2 + 1], wa * v.y);
            unsafeAtomicAdd(&out_f[((size_t)r * NX + y1) * 2], wb * v.x);
            unsafeAtomicAdd(&out_f[((size_t)r * NX + y1) * 2 + 1], wb * v.y);
          }
        }
      }
    }
  }
  __syncthreads();
  __half2* dst = out_p + (size_t)(seg * NT + t) * NX * NX + (size_t)r0 * NX;
  for (int i = tid; i < BR * NX; i += 1024) dst[i] = acc[i];
}

// out = out_f + sum_{seg,t} out_p (half2 slices)
__global__ __launch_bounds__(256) void reduce_k(
    const __half2* __restrict__ out_p, const float* __restrict__ out_f,
    float* __restrict__ out, int nslice) {
  const int n = NX * NX;  // 102400 cells
  int i = blockIdx.x * 256 + threadIdx.x;
  if (i >= n) return;
  float2 s = ((const float2*)out_f)[i];
  for (int k = 0; k < nslice; ++k) {
    float2 v = __half22float2(out_p[(size_t)k * n + i]);
    s.x += v.x;
    s.y += v.y;
  }
  ((float2*)out)[i] = s;
}

extern "C" void kernel_launch(void* const* d_in, const int* in_sizes, int n_in,
                              void* d_out, int out_size, void* d_ws,
                              size_t ws_size, hipStream_t stream) {
  const float* kr = (const float*)d_in[0];
  const float* ki = (const float*)d_in[1];
  const float* mask = (const float*)d_in[2];
  const float* sr = (const float*)d_in[3];
  const float* si = (const float*)d_in[4];
  const float* fl = (const float*)d_in[5];
  float* out = (float*)d_out;

  const size_t tmp1 = (size_t)NT * NX * NX * 4;      // fp16 complex, per coil
  const size_t kT_b = (size_t)NC * NX * NX * 8;
  const size_t sT_b = (size_t)NC * NX * NX * 4;      // half2
  const size_t fs_b = (size_t)NT * NX * NX * 8;
  const size_t mp_b = (size_t)NC * NX * NX * 4;
  const size_t ia_b = (size_t)NT * NX * NX * 4;      // half2
  const size_t of_b = (size_t)NX * NX * 8;
  const size_t op1 = (size_t)NT * NX * NX * 4;       // half2, per segment

  int NSEG = 2, G = 16;
  for (;;) {
    size_t fixed = kT_b + sT_b + fs_b + mp_b + ia_b + of_b + NSEG * op1;
    if (ws_size >= fixed + (size_t)G * tmp1) break;
    if (G > 1) { G >>= 1; continue; }
    if (NSEG > 1) { NSEG >>= 1; G = 16; continue; }
    break;  // minimal config; assume it fits
  }

  char* w = (char*)d_ws;
  __half2* tmp = (__half2*)w;    w += (size_t)G * tmp1;
  float2* kT = (float2*)w;       w += kT_b;
  __half2* sT = (__half2*)w;     w += sT_b;
  float2* fs = (float2*)w;       w += fs_b;
  __half2* im_aux = (__half2*)w; w += ia_b;
  __half2* out_p = (__half2*)w;  w += (size_t)NSEG * op1;
  float* out_f = (float*)w;      w += of_b;
  unsigned int* mp = (unsigned int*)w;

  hipMemsetAsync(out_f, 0, of_b, stream);
  prep_mask_k<<<6400, 256, 0, stream>>>(mask, mp);
  prep_kspace_k<<<6400, 256, 0, stream>>>(kr, ki, kT);
  prep_smaps_k<<<6400, 256, 0, stream>>>(sr, si, sT);
  prep_flow_k<<<3200, 256, 0, stream>>>(fl, fs);

  for (int c0 = 0; c0 < NC; c0 += G) {
    pass1_k<<<dim3(NX, G), 256, 0, stream>>>(kT, mp, tmp, c0);
    pass2_k<<<dim3(80, NT), 256, 0, stream>>>(tmp, sT, im_aux, c0, G,
                                              c0 == 0 ? 1 : 0);
  }
  scatter_k<<<dim3(NX / BR, NSEG, NT), 1024, 0, stream>>>(im_aux, fs, out_p,
                                                          out_f, NSEG);
  reduce_k<<<400, 256, 0, stream>>>(out_p, out_f, out, NSEG * NT);
}

// Round 18
// 256.061 us; speedup vs baseline: 1.1170x; 1.1170x over previous
//
#include <hip/hip_runtime.h>
#include <hip/hip_fp16.h>

// MRI adjoint: masked centered 2D IFFT per (coil,frame) -> conj(smaps) combine
// -> bilinear warp-adjoint scatter -> sum over frames. Nx=Ny=320, Nc=16, Nt=25.
//
// FFT (round-18): fp16-PACKED butterflies -- complex (re,im) in one __half2,
// v_pk_fma_f16 ops: 4 packed VALU/point/stage vs 6 scalar f32 (round-17
// attribution: pass1+pass2 ~150us, both VALU-bound on scalar complex math).
// 320 = 5*64, one wave per transform; selection-free z = cmul(o+sg*z, w);
// radix-5 twiddles folded into the identity-twiddle m=1 stage.
// Cross-lane: m=1,2 DPP quad_perm; m=4,8,16 ds_swizzle; m=32 shfl_xor.
// Signs folded into pass1 output & pre-signed smaps. tmp/smaps/im_aux fp16.
// prep: round-15 merged kernel (float4 y-major mask; 7.5KB LDS overlay).
// Scatter: LDS __half2 accumulator + ds_pk_add_f16 taps.

#define NX 320
#define NT 25
#define NC 16
#define BR 32
#define WH 16
static const float INV320 = 1.0f / 320.0f;

typedef float v2f __attribute__((ext_vector_type(2)));
typedef unsigned int u32;

__device__ __forceinline__ int rev6(int l) {
  return ((l & 1) << 5) | ((l & 2) << 3) | ((l & 4) << 1) |
         ((l & 8) >> 1) | ((l & 16) >> 3) | ((l & 32) >> 5);
}

__device__ __forceinline__ u32 h2u(__half2 h) {
  return *reinterpret_cast<u32*>(&h);
}
__device__ __forceinline__ __half2 u2h(u32 u) {
  return *reinterpret_cast<__half2*>(&u);
}
__device__ __forceinline__ __half2 swap16(__half2 h) {
  u32 u = h2u(h);
  u = (u >> 16) | (u << 16);  // rotate -> v_alignbit_b32
  return u2h(u);
}

// Cross-lane xor exchange on 32-bit payload. m=1,2: DPP quad_perm (VALU).
// m=4,8,16: immediate ds_swizzle. m=32: shfl_xor.
template <int M>
__device__ __forceinline__ u32 lxoru(u32 x) {
  if constexpr (M == 1) {
    return (u32)__builtin_amdgcn_mov_dpp((int)x, 0xB1, 0xF, 0xF, true);
  } else if constexpr (M == 2) {
    return (u32)__builtin_amdgcn_mov_dpp((int)x, 0x4E, 0xF, 0xF, true);
  } else if constexpr (M == 32) {
    return (u32)__shfl_xor((int)x, 32);
  } else {
    constexpr int pat = (M << 10) | 0x1F;  // BitMode: xor=M, and=0x1F
    return (u32)__builtin_amdgcn_ds_swizzle((int)x, pat);
  }
}

// Lane-resident packed twiddle state. Per stage st=0..4 (m=32..2):
// sg=(±1,±1), c2=(c,c) (top lanes (1,1)), s2n=(-s,s) (top (0,0)).
// m=1 stage: sg5 + folded radix-5 twiddles w5c=(c,c), w5s=(-s,s), q=1..4.
struct TwH {
  __half2 sg[5], c2[5], s2n[5];
  __half2 sg5;
  __half2 w5c[4], w5s[4];
  __half2 C1h, C2h, S1h, nS1h, S2h, NP;
};

__device__ __forceinline__ void make_twh(int lane, TwH& tw) {
#pragma unroll
  for (int st = 0; st < 5; ++st) {
    int m = 32 >> st;
    bool bot = (lane & m) != 0;
    int j = lane & (m - 1);
    float ang = 3.14159265358979323846f * (float)j / (float)m;
    float s, c;
    __sincosf(ang, &s, &c);
    float g = bot ? -1.f : 1.f;
    float cc = bot ? c : 1.f, ss = bot ? s : 0.f;
    tw.sg[st] = __floats2half2_rn(g, g);
    tw.c2[st] = __floats2half2_rn(cc, cc);
    tw.s2n[st] = __floats2half2_rn(-ss, ss);
  }
  float g5 = (lane & 1) ? -1.f : 1.f;
  tw.sg5 = __floats2half2_rn(g5, g5);
  int k1 = rev6(lane);
  float b = (6.283185307179586f / 320.0f) * (float)k1;
  float s1, c1;
  __sincosf(b, &s1, &c1);
  float cq = 1.f, sq = 0.f;
#pragma unroll
  for (int q = 1; q < 5; ++q) {
    float nc = cq * c1 - sq * s1, ns = cq * s1 + sq * c1;
    cq = nc;
    sq = ns;
    tw.w5c[q - 1] = __floats2half2_rn(cq, cq);
    tw.w5s[q - 1] = __floats2half2_rn(-sq, sq);
  }
  const float C1 = 0.30901699437494742f, S1 = 0.95105651629515357f;
  const float C2 = -0.80901699437494742f, S2 = 0.58778525229247312f;
  tw.C1h = __floats2half2_rn(C1, C1);
  tw.C2h = __floats2half2_rn(C2, C2);
  tw.S1h = __floats2half2_rn(S1, S1);
  tw.nS1h = __floats2half2_rn(-S1, -S1);
  tw.S2h = __floats2half2_rn(S2, S2);
  tw.NP = __floats2half2_rn(-1.f, 1.f);
}

// packed cmul: (x,y)*(c+is) = (cx - sy, cy + sx)
__device__ __forceinline__ __half2 cmul_h(__half2 t, __half2 c2, __half2 s2n) {
  return __hfma2(s2n, swap16(t), __hmul2(c2, t));
}

template <int M>
__device__ __forceinline__ void bstage_h(__half2 z[5], __half2 sg, __half2 c2,
                                         __half2 s2n) {
#pragma unroll
  for (int q = 0; q < 5; ++q) {
    __half2 o = u2h(lxoru<M>(h2u(z[q])));
    __half2 t = __hfma2(sg, z[q], o);
    z[q] = cmul_h(t, c2, s2n);  // top lanes: identity twiddle
  }
}

// Unnormalized inverse 320-pt DFT, fp16 packed: lane l enters with x[5l+q]
// in z[q]; exits with X[rev6(l) + 64*q].
__device__ __forceinline__ void fft320h(__half2 z[5], const TwH& tw) {
  bstage_h<32>(z, tw.sg[0], tw.c2[0], tw.s2n[0]);
  bstage_h<16>(z, tw.sg[1], tw.c2[1], tw.s2n[1]);
  bstage_h<8>(z, tw.sg[2], tw.c2[2], tw.s2n[2]);
  bstage_h<4>(z, tw.sg[3], tw.c2[3], tw.s2n[3]);
  bstage_h<2>(z, tw.sg[4], tw.c2[4], tw.s2n[4]);
  {
    __half2 o = u2h(lxoru<1>(h2u(z[0])));
    z[0] = __hfma2(tw.sg5, z[0], o);  // w5[0] = 1: no cmul
#pragma unroll
    for (int q = 1; q < 5; ++q) {
      o = u2h(lxoru<1>(h2u(z[q])));
      __half2 t = __hfma2(tw.sg5, z[q], o);
      z[q] = cmul_h(t, tw.w5c[q - 1], tw.w5s[q - 1]);
    }
  }
  __half2 t0 = z[0], t1 = z[1], t2 = z[2], t3 = z[3], t4 = z[4];
  __half2 a1 = __hadd2(t1, t4), b1 = __hsub2(t1, t4);
  __half2 a2 = __hadd2(t2, t3), b2 = __hsub2(t2, t3);
  z[0] = __hadd2(t0, __hadd2(a1, a2));
  __half2 p = __hfma2(tw.C2h, a2, __hfma2(tw.C1h, a1, t0));
  __half2 q_ = __hfma2(tw.S2h, b2, __hmul2(tw.S1h, b1));
  __half2 r = __hfma2(tw.C1h, a2, __hfma2(tw.C2h, a1, t0));
  __half2 u = __hfma2(tw.nS1h, b2, __hmul2(tw.S2h, b1));
  __half2 qi = __hmul2(tw.NP, swap16(q_));  // i*q
  __half2 ui = __hmul2(tw.NP, swap16(u));
  z[1] = __hadd2(p, qi);
  z[4] = __hsub2(p, qi);
  z[2] = __hadd2(r, ui);
  z[3] = __hsub2(r, ui);
}

// Merged pre-pass: role-switched on blockIdx.x. ONE overlaid LDS buffer.
//  [0,6400)      mask [x][y][c][t] -> bit-packed mp[c][y][x] (float4, y-major)
//  [6400,12800)  kspace [x][y][c] -> kT[c][y][x] float2
//  [12800,19200) smaps [x][y][c] -> sT[c][x][y] half2, pre-signed by (-1)^y
//  [19200,22400) flow [nx][ny][2][t] -> fs[t][nx][ny] float2 (float2 loads)
//  [22400,22600) zero out_f
__global__ __launch_bounds__(256) void prep_k(
    const float* __restrict__ mask, const float* __restrict__ kr,
    const float* __restrict__ ki, const float* __restrict__ sr,
    const float* __restrict__ si, const float* __restrict__ fl,
    unsigned int* __restrict__ mp, float2* __restrict__ kT,
    __half2* __restrict__ sT, float2* __restrict__ fs,
    float* __restrict__ out_f) {
  __shared__ __align__(16) char shmem[7552];  // overlaid by all phases
  int bid = blockIdx.x, tid = threadIdx.x;
  if (bid < 6400) {
    // y-major: consecutive blocks read adjacent 1600B chunks (16 seq streams)
    int xt = bid / 320, y = bid % 320;
    int w = tid >> 6, lane = tid & 63;
    float4* stage4 = (float4*)shmem;                      // [4][100]
    float* stage = (float*)shmem;
    unsigned int* tileu = (unsigned int*)(shmem + 6400);  // [16][17]
#pragma unroll
    for (int k = 0; k < 4; ++k) {
      int xx = w * 4 + k;
      const float4* src =
          (const float4*)(mask + ((size_t)((xt * 16 + xx) * NX) + y) * (NC * NT));
      float4* dst4 = stage4 + w * 100;
      if (lane < 50) {
        dst4[lane] = src[lane];           // 1KB/wave-instr
        dst4[lane + 50] = src[lane + 50];
      }
      if (lane < 16) {
        const float* row = stage + w * 400 + lane * NT;
        unsigned int bits = 0;
#pragma unroll
        for (int t = 0; t < NT; ++t) bits |= (row[t] != 0.f) ? (1u << t) : 0u;
        tileu[xx * 17 + lane] = bits;
      }
    }
    __syncthreads();
    int c2 = tid >> 4, xx2 = tid & 15;
    mp[((size_t)(c2 * NX + y)) * NX + xt * 16 + xx2] = tileu[xx2 * 17 + c2];
  } else if (bid < 12800) {
    int r = bid - 6400;
    int xt = r % 20, y = r / 20;
    int xx = tid >> 4, c = tid & 15;
    float2* tilef = (float2*)shmem;  // [16][17]
    size_t si_ = (size_t)((xt * 16 + xx) * NX + y) * NC + c;
    tilef[xx * 17 + c] = make_float2(kr[si_], ki[si_]);
    __syncthreads();
    int c2 = tid >> 4, xx2 = tid & 15;
    kT[((size_t)(c2 * NX + y)) * NX + xt * 16 + xx2] = tilef[xx2 * 17 + c2];
  } else if (bid < 19200) {
    int r = bid - 12800;
    int yt = r % 20, x = r / 20;
    int yy = tid >> 4, c = tid & 15;
    float2* tiles = (float2*)shmem;  // [16][17]
    size_t si_ = (size_t)(x * NX + yt * 16 + yy) * NC + c;
    tiles[yy * 17 + c] = make_float2(sr[si_], si[si_]);
    __syncthreads();
    int c2 = tid >> 4, yy2 = tid & 15;
    float2 v = tiles[yy2 * 17 + c2];
    float sg = (yy2 & 1) ? -1.f : 1.f;  // (-1)^ny pre-sign
    sT[((size_t)(c2 * NX + x)) * NX + yt * 16 + yy2] =
        __floats2half2_rn(v.x * sg, v.y * sg);
  } else if (bid < 22400) {
    int r = bid - 19200;
    int nyt = r % 10, nx = r / 10;
    float* buf = (float*)shmem;  // [1600]
    size_t base = (size_t)(nx * NX + nyt * 32) * (2 * NT);
    const float2* src2 = (const float2*)(fl + base);  // 8B-aligned
    float2* buf2 = (float2*)shmem;
    for (int f = tid; f < 800; f += 256) buf2[f] = src2[f];
    __syncthreads();
    for (int f = tid; f < 1600; f += 256) {
      int t = f / 64;
      int k = f % 64;
      int nyl = k >> 1, d = k & 1;
      size_t di = ((size_t)(t * NX + nx) * NX + nyt * 32 + nyl) * 2 + d;
      ((float*)fs)[di] = buf[(nyl * 2 + d) * NT + t];
    }
  } else {
    int idx = (bid - 22400) * 256 + tid;  // 51200 float4
    ((float4*)out_f)[idx] = make_float4(0.f, 0.f, 0.f, 0.f);
  }
}

// Pass 1: x-axis IFFT for coil chunk [c0, c0+G). Writes tmp[cg][t][ky][nx]
// fp16, pre-signed by (-1)^nx * (-1)^ky. FFT fully fp16-packed.
__global__ __launch_bounds__(256) void pass1_k(
    const float2* __restrict__ kT, const unsigned int* __restrict__ mp,
    __half2* __restrict__ tmp, int c0) {
  int y = blockIdx.x, cg = blockIdx.y, c = c0 + cg;
  int tid = threadIdx.x, lane = tid & 63, w = tid >> 6;
  __half2 v[5];
  unsigned int mb[5];
  size_t rowbase = ((size_t)c * NX + y) * NX;
#pragma unroll
  for (int q = 0; q < 5; ++q) {
    int x = 5 * lane + q;
    float2 kv = kT[rowbase + x];
    float sg = ((lane + q) & 1) ? -INV320 : INV320;  // (-1)^x / 320
    v[q] = __floats2half2_rn(kv.x * sg, kv.y * sg);
    mb[q] = mp[rowbase + x];
  }
  TwH tw;
  make_twh(lane, tw);
  int r6 = rev6(lane);
  float osg = ((lane & 32) ? -1.f : 1.f) * ((y & 1) ? -1.f : 1.f);
  __half2 osg2 = __floats2half2_rn(osg, osg);
  for (int t = w; t < NT; t += 4) {
    __half2 z[5];
#pragma unroll
    for (int q = 0; q < 5; ++q)
      z[q] = u2h(((mb[q] >> t) & 1u) ? h2u(v[q]) : 0u);
    fft320h(z, tw);
    __half2* dst = tmp + ((size_t)(cg * NT + t) * NX + y) * NX;
#pragma unroll
    for (int k2 = 0; k2 < 5; ++k2) dst[r6 + 64 * k2] = __hmul2(osg2, z[k2]);
  }
}

// Pass 2: y-axis IFFT (fp16-packed) + conj(smaps) f32 MAC -> im_aux fp16.
// 256 threads = 4 waves; block = (nx-tile of 4, t); wave j owns nx.
__global__ __launch_bounds__(256) void pass2_k(
    const __half2* __restrict__ tmp, const __half2* __restrict__ sT,
    __half2* __restrict__ im_aux, int c0, int G, int first) {
  int bx = blockIdx.x, t = blockIdx.y;
  int nxt_ = (bx >> 3) + 10 * (bx & 7);  // bijective on [0,80)
  int tid = threadIdx.x, lane = tid & 63, j = tid >> 6;
  int nx = nxt_ * 4 + j;
  int k1 = rev6(lane);
  TwH tw;
  make_twh(lane, tw);
  __shared__ __half2 tile[2][NX][5];  // 12.8 KB
  v2f acc[5] = {{0, 0}, {0, 0}, {0, 0}, {0, 0}, {0, 0}};

  int off[5], lw[5];
#pragma unroll
  for (int q = 0; q < 5; ++q) {
    int f = tid + q * 256;
    off[q] = (f >> 2) * NX + (f & 3);
    lw[q] = (f >> 2) * 5 + (f & 3);
  }
  const size_t pstride = (size_t)NT * NX * NX;
  const __half2* sbase = tmp + (size_t)t * NX * NX + nxt_ * 4;
  __half2* lds = &tile[0][0][0];

  __half2 nb[5];
#pragma unroll
  for (int q = 0; q < 5; ++q) nb[q] = sbase[off[q]];

  for (int cg = 0; cg < G; ++cg) {
    __half2 cb[5];
#pragma unroll
    for (int q = 0; q < 5; ++q) cb[q] = nb[q];
    if (cg + 1 < G) {
      const __half2* s = sbase + (size_t)(cg + 1) * pstride;
#pragma unroll
      for (int q = 0; q < 5; ++q) nb[q] = s[off[q]];  // in flight across iter
    }
    __half2* buf = lds + (cg & 1) * (NX * 5);
#pragma unroll
    for (int q = 0; q < 5; ++q) buf[lw[q]] = cb[q];
    const __half2* srow = sT + ((size_t)(c0 + cg) * NX + nx) * NX;
    __half2 smh[5];
#pragma unroll
    for (int k2 = 0; k2 < 5; ++k2) smh[k2] = srow[k1 + 64 * k2];
    __syncthreads();
    __half2 z[5];
#pragma unroll
    for (int q = 0; q < 5; ++q) z[q] = buf[(5 * lane + q) * 5 + j];
    fft320h(z, tw);
#pragma unroll
    for (int k2 = 0; k2 < 5; ++k2) {
      float2 sm = __half22float2(smh[k2]);
      float2 zf = __half22float2(z[k2]);
      v2f zv = {zf.x, zf.y};
      v2f zc = {zf.y, -zf.x};  // conj-MAC helper
      acc[k2] += sm.x * zv + sm.y * zc;
    }
  }
  __half2* dst = im_aux + ((size_t)t * NX + nx) * NX;
#pragma unroll
  for (int k2 = 0; k2 < 5; ++k2) {
    int ny = k1 + 64 * k2;
    v2f nv = acc[k2];  // (-1)^ny folded into sT
    if (!first) {
      float2 old = __half22float2(dst[ny]);
      nv.x += old.x;
      nv.y += old.y;
    }
    dst[ny] = __floats2half2_rn(nv.x, nv.y);
  }
}

// Scatter: block (band b, seg, frame t). LDS-privatized 32-row band of
// __half2 (re,im) cells; taps via ds_pk_add_f16 (4 lane-atomics/element).
__global__ __launch_bounds__(1024) void scatter_k(
    const __half2* __restrict__ im, const float2* __restrict__ fs,
    __half2* __restrict__ out_p, float* __restrict__ out_f, int nseg) {
  int b = blockIdx.x, seg = blockIdx.y, t = blockIdx.z;
  int r0 = b * BR;
  int tid = threadIdx.x, lane = tid & 63, w = tid >> 6;
  __shared__ __half2 acc[BR * NX];  // 40 KB
  const __half2 h2z = __floats2half2_rn(0.f, 0.f);
  for (int i = tid; i < BR * NX; i += 1024) acc[i] = h2z;
  __syncthreads();
  int lo = max(r0 - WH, 0), hi = min(r0 + BR + WH, NX);
  int stride = 16 * nseg;
  for (int nx = lo + seg * 16 + w; nx < hi; nx += stride) {
    bool own = (nx >= r0) && (nx < r0 + BR);
    const __half2* imrow = im + ((size_t)t * NX + nx) * NX;
    const float2* frow = fs + ((size_t)t * NX + nx) * NX;
#pragma unroll
    for (int q = 0; q < 5; ++q) {
      int ny = lane + 64 * q;
      float2 v = __half22float2(imrow[ny]);
      float2 fl = frow[ny];
      float px = fminf(fmaxf((float)nx + fl.x, 0.f), 319.f);
      float py = fminf(fmaxf((float)ny + fl.y, 0.f), 319.f);
      int x0 = (int)floorf(px), y0 = (int)floorf(py);
      int x1 = min(x0 + 1, NX - 1), y1 = min(y0 + 1, NX - 1);
      float wx = px - (float)x0, wy = py - (float)y0;
      float w00 = (1.f - wx) * (1.f - wy), w01 = (1.f - wx) * wy;
      float w10 = wx * (1.f - wy), w11 = wx * wy;
#pragma unroll
      for (int half = 0; half < 2; ++half) {
        int r = half ? x1 : x0;
        float wa = half ? w10 : w00;
        float wb = half ? w11 : w01;
        if (r >= r0 && r < r0 + BR) {
          unsafeAtomicAdd(&acc[(r - r0) * NX + y0],
                          __floats2half2_rn(wa * v.x, wa * v.y));
          unsafeAtomicAdd(&acc[(r - r0) * NX + y1],
                          __floats2half2_rn(wb * v.x, wb * v.y));
        } else if (own) {
          int rb = (r / BR) * BR;
          if (nx < rb - WH || nx >= rb + BR + WH) {  // no band reads nx
            unsafeAtomicAdd(&out_f[((size_t)r * NX + y0) * 2], wa * v.x);
            unsafeAtomicAdd(&out_f[((size_t)r * NX + y0) * 2 + 1], wa * v.y);
            unsafeAtomicAdd(&out_f[((size_t)r * NX + y1) * 2], wb * v.x);
            unsafeAtomicAdd(&out_f[((size_t)r * NX + y1) * 2 + 1], wb * v.y);
          }
        }
      }
    }
  }
  __syncthreads();
  __half2* dst = out_p + (size_t)(seg * NT + t) * NX * NX + (size_t)r0 * NX;
  for (int i = tid; i < BR * NX; i += 1024) dst[i] = acc[i];
}

// out = out_f + sum_{seg,t} out_p (half2 slices)
__global__ __launch_bounds__(256) void reduce_k(
    const __half2* __restrict__ out_p, const float* __restrict__ out_f,
    float* __restrict__ out, int nslice) {
  const int n = NX * NX;  // 102400 cells
  int i = blockIdx.x * 256 + threadIdx.x;
  if (i >= n) return;
  float2 s = ((const float2*)out_f)[i];
  for (int k = 0; k < nslice; ++k) {
    float2 v = __half22float2(out_p[(size_t)k * n + i]);
    s.x += v.x;
    s.y += v.y;
  }
  ((float2*)out)[i] = s;
}

extern "C" void kernel_launch(void* const* d_in, const int* in_sizes, int n_in,
                              void* d_out, int out_size, void* d_ws,
                              size_t ws_size, hipStream_t stream) {
  const float* kr = (const float*)d_in[0];
  const float* ki = (const float*)d_in[1];
  const float* mask = (const float*)d_in[2];
  const float* sr = (const float*)d_in[3];
  const float* si = (const float*)d_in[4];
  const float* fl = (const float*)d_in[5];
  float* out = (float*)d_out;

  const size_t tmp1 = (size_t)NT * NX * NX * 4;      // fp16 complex, per coil
  const size_t kT_b = (size_t)NC * NX * NX * 8;
  const size_t sT_b = (size_t)NC * NX * NX * 4;      // half2
  const size_t fs_b = (size_t)NT * NX * NX * 8;
  const size_t mp_b = (size_t)NC * NX * NX * 4;
  const size_t ia_b = (size_t)NT * NX * NX * 4;      // half2
  const size_t of_b = (size_t)NX * NX * 8;
  const size_t op1 = (size_t)NT * NX * NX * 4;       // half2, per segment

  int NSEG = 2, G = 16;
  for (;;) {
    size_t fixed = kT_b + sT_b + fs_b + mp_b + ia_b + of_b + NSEG * op1;
    if (ws_size >= fixed + (size_t)G * tmp1) break;
    if (G > 1) { G >>= 1; continue; }
    if (NSEG > 1) { NSEG >>= 1; G = 16; continue; }
    break;  // minimal config; assume it fits
  }

  char* w = (char*)d_ws;
  __half2* tmp = (__half2*)w;    w += (size_t)G * tmp1;
  float2* kT = (float2*)w;       w += kT_b;
  __half2* sT = (__half2*)w;     w += sT_b;
  float2* fs = (float2*)w;       w += fs_b;
  __half2* im_aux = (__half2*)w; w += ia_b;
  __half2* out_p = (__half2*)w;  w += (size_t)NSEG * op1;
  float* out_f = (float*)w;      w += of_b;
  unsigned int* mp = (unsigned int*)w;

  prep_k<<<22600, 256, 0, stream>>>(mask, kr, ki, sr, si, fl, mp, kT, sT, fs,
                                    out_f);

  for (int c0 = 0; c0 < NC; c0 += G) {
    pass1_k<<<dim3(NX, G), 256, 0, stream>>>(kT, mp, tmp, c0);
    pass2_k<<<dim3(80, NT), 256, 0, stream>>>(tmp, sT, im_aux, c0, G,
                                              c0 == 0 ? 1 : 0);
  }
  scatter_k<<<dim3(NX / BR, NSEG, NT), 1024, 0, stream>>>(im_aux, fs, out_p,
                                                          out_f, NSEG);
  reduce_k<<<400, 256, 0, stream>>>(out_p, out_f, out, NSEG * NT);
}

// Round 20
// 246.600 us; speedup vs baseline: 1.1599x; 1.0384x over previous
//
#include <hip/hip_runtime.h>
#include <hip/hip_fp16.h>

// MRI adjoint: masked centered 2D IFFT per (coil,frame) -> conj(smaps) combine
// -> bilinear warp-adjoint scatter -> sum over frames. Nx=Ny=320, Nc=16, Nt=25.
//
// FFT: fp16-PACKED butterflies (round-18: 4 packed VALU/point/stage), one wave
// per 320-pt transform (5*64); selection-free z = cmul(o+sg*z, w); radix-5
// twiddles folded into the identity-twiddle m=1 stage. Cross-lane: m=1,2 DPP
// quad_perm; m=4,8,16 ds_swizzle; m=32 shfl_xor.
// Round-20 (= round-19 fixed): smaps/flow transposes + out_f zero moved into
// pass1's launch as role-switched blocks (BW-bound work overlaps VALU-bound
// FFT blocks); prep_k = mask+kspace only with NON-TEMPORAL mask loads via a
// native ext_vector float4 (HIP_vector_type rejected by the builtin).
// tmp/smaps/im_aux fp16. Scatter: LDS __half2 accumulator + ds_pk_add_f16.

#define NX 320
#define NT 25
#define NC 16
#define BR 32
#define WH 16
static const float INV320 = 1.0f / 320.0f;

typedef float v2f __attribute__((ext_vector_type(2)));
typedef float nv4f __attribute__((ext_vector_type(4)));  // nt-load-compatible
typedef unsigned int u32;

__device__ __forceinline__ int rev6(int l) {
  return ((l & 1) << 5) | ((l & 2) << 3) | ((l & 4) << 1) |
         ((l & 8) >> 1) | ((l & 16) >> 3) | ((l & 32) >> 5);
}

__device__ __forceinline__ u32 h2u(__half2 h) {
  return *reinterpret_cast<u32*>(&h);
}
__device__ __forceinline__ __half2 u2h(u32 u) {
  return *reinterpret_cast<__half2*>(&u);
}
__device__ __forceinline__ __half2 swap16(__half2 h) {
  u32 u = h2u(h);
  u = (u >> 16) | (u << 16);  // rotate -> v_alignbit_b32
  return u2h(u);
}

// Cross-lane xor exchange on 32-bit payload. m=1,2: DPP quad_perm (VALU).
// m=4,8,16: immediate ds_swizzle. m=32: shfl_xor.
template <int M>
__device__ __forceinline__ u32 lxoru(u32 x) {
  if constexpr (M == 1) {
    return (u32)__builtin_amdgcn_mov_dpp((int)x, 0xB1, 0xF, 0xF, true);
  } else if constexpr (M == 2) {
    return (u32)__builtin_amdgcn_mov_dpp((int)x, 0x4E, 0xF, 0xF, true);
  } else if constexpr (M == 32) {
    return (u32)__shfl_xor((int)x, 32);
  } else {
    constexpr int pat = (M << 10) | 0x1F;  // BitMode: xor=M, and=0x1F
    return (u32)__builtin_amdgcn_ds_swizzle((int)x, pat);
  }
}

// Lane-resident packed twiddle state. Per stage st=0..4 (m=32..2):
// sg=(±1,±1), c2=(c,c) (top lanes (1,1)), s2n=(-s,s) (top (0,0)).
// m=1 stage: sg5 + folded radix-5 twiddles w5c=(c,c), w5s=(-s,s), q=1..4.
struct TwH {
  __half2 sg[5], c2[5], s2n[5];
  __half2 sg5;
  __half2 w5c[4], w5s[4];
  __half2 C1h, C2h, S1h, nS1h, S2h, NP;
};

__device__ __forceinline__ void make_twh(int lane, TwH& tw) {
#pragma unroll
  for (int st = 0; st < 5; ++st) {
    int m = 32 >> st;
    bool bot = (lane & m) != 0;
    int j = lane & (m - 1);
    float ang = 3.14159265358979323846f * (float)j / (float)m;
    float s, c;
    __sincosf(ang, &s, &c);
    float g = bot ? -1.f : 1.f;
    float cc = bot ? c : 1.f, ss = bot ? s : 0.f;
    tw.sg[st] = __floats2half2_rn(g, g);
    tw.c2[st] = __floats2half2_rn(cc, cc);
    tw.s2n[st] = __floats2half2_rn(-ss, ss);
  }
  float g5 = (lane & 1) ? -1.f : 1.f;
  tw.sg5 = __floats2half2_rn(g5, g5);
  int k1 = rev6(lane);
  float b = (6.283185307179586f / 320.0f) * (float)k1;
  float s1, c1;
  __sincosf(b, &s1, &c1);
  float cq = 1.f, sq = 0.f;
#pragma unroll
  for (int q = 1; q < 5; ++q) {
    float nc = cq * c1 - sq * s1, ns = cq * s1 + sq * c1;
    cq = nc;
    sq = ns;
    tw.w5c[q - 1] = __floats2half2_rn(cq, cq);
    tw.w5s[q - 1] = __floats2half2_rn(-sq, sq);
  }
  const float C1 = 0.30901699437494742f, S1 = 0.95105651629515357f;
  const float C2 = -0.80901699437494742f, S2 = 0.58778525229247312f;
  tw.C1h = __floats2half2_rn(C1, C1);
  tw.C2h = __floats2half2_rn(C2, C2);
  tw.S1h = __floats2half2_rn(S1, S1);
  tw.nS1h = __floats2half2_rn(-S1, -S1);
  tw.S2h = __floats2half2_rn(S2, S2);
  tw.NP = __floats2half2_rn(-1.f, 1.f);
}

// packed cmul: (x,y)*(c+is) = (cx - sy, cy + sx)
__device__ __forceinline__ __half2 cmul_h(__half2 t, __half2 c2, __half2 s2n) {
  return __hfma2(s2n, swap16(t), __hmul2(c2, t));
}

template <int M>
__device__ __forceinline__ void bstage_h(__half2 z[5], __half2 sg, __half2 c2,
                                         __half2 s2n) {
#pragma unroll
  for (int q = 0; q < 5; ++q) {
    __half2 o = u2h(lxoru<M>(h2u(z[q])));
    __half2 t = __hfma2(sg, z[q], o);
    z[q] = cmul_h(t, c2, s2n);  // top lanes: identity twiddle
  }
}

// Unnormalized inverse 320-pt DFT, fp16 packed: lane l enters with x[5l+q]
// in z[q]; exits with X[rev6(l) + 64*q].
__device__ __forceinline__ void fft320h(__half2 z[5], const TwH& tw) {
  bstage_h<32>(z, tw.sg[0], tw.c2[0], tw.s2n[0]);
  bstage_h<16>(z, tw.sg[1], tw.c2[1], tw.s2n[1]);
  bstage_h<8>(z, tw.sg[2], tw.c2[2], tw.s2n[2]);
  bstage_h<4>(z, tw.sg[3], tw.c2[3], tw.s2n[3]);
  bstage_h<2>(z, tw.sg[4], tw.c2[4], tw.s2n[4]);
  {
    __half2 o = u2h(lxoru<1>(h2u(z[0])));
    z[0] = __hfma2(tw.sg5, z[0], o);  // w5[0] = 1: no cmul
#pragma unroll
    for (int q = 1; q < 5; ++q) {
      o = u2h(lxoru<1>(h2u(z[q])));
      __half2 t = __hfma2(tw.sg5, z[q], o);
      z[q] = cmul_h(t, tw.w5c[q - 1], tw.w5s[q - 1]);
    }
  }
  __half2 t0 = z[0], t1 = z[1], t2 = z[2], t3 = z[3], t4 = z[4];
  __half2 a1 = __hadd2(t1, t4), b1 = __hsub2(t1, t4);
  __half2 a2 = __hadd2(t2, t3), b2 = __hsub2(t2, t3);
  z[0] = __hadd2(t0, __hadd2(a1, a2));
  __half2 p = __hfma2(tw.C2h, a2, __hfma2(tw.C1h, a1, t0));
  __half2 q_ = __hfma2(tw.S2h, b2, __hmul2(tw.S1h, b1));
  __half2 r = __hfma2(tw.C1h, a2, __hfma2(tw.C2h, a1, t0));
  __half2 u = __hfma2(tw.nS1h, b2, __hmul2(tw.S2h, b1));
  __half2 qi = __hmul2(tw.NP, swap16(q_));  // i*q
  __half2 ui = __hmul2(tw.NP, swap16(u));
  z[1] = __hadd2(p, qi);
  z[4] = __hsub2(p, qi);
  z[2] = __hadd2(r, ui);
  z[3] = __hsub2(r, ui);
}

// prep: mask + kspace only (smaps/flow/out_f moved into pass1's launch).
//  [0,6400)      mask [x][y][c][t] -> bit-packed mp[c][y][x]
//                (float4 NON-TEMPORAL y-major streams)
//  [6400,12800)  kspace [x][y][c] -> kT[c][y][x] float2
__global__ __launch_bounds__(256) void prep_k(
    const float* __restrict__ mask, const float* __restrict__ kr,
    const float* __restrict__ ki, unsigned int* __restrict__ mp,
    float2* __restrict__ kT) {
  __shared__ __align__(16) char shmem[7552];
  int bid = blockIdx.x, tid = threadIdx.x;
  if (bid < 6400) {
    int xt = bid / 320, y = bid % 320;  // y-major: adjacent 1600B chunks
    int w = tid >> 6, lane = tid & 63;
    nv4f* stage4 = (nv4f*)shmem;                          // [4][100]
    float* stage = (float*)shmem;
    unsigned int* tileu = (unsigned int*)(shmem + 6400);  // [16][17]
#pragma unroll
    for (int k = 0; k < 4; ++k) {
      int xx = w * 4 + k;
      const nv4f* src =
          (const nv4f*)(mask + ((size_t)((xt * 16 + xx) * NX) + y) * (NC * NT));
      nv4f* dst4 = stage4 + w * 100;
      if (lane < 50) {
        dst4[lane] = __builtin_nontemporal_load(&src[lane]);
        dst4[lane + 50] = __builtin_nontemporal_load(&src[lane + 50]);
      }
      if (lane < 16) {
        const float* row = stage + w * 400 + lane * NT;
        unsigned int bits = 0;
#pragma unroll
        for (int t = 0; t < NT; ++t) bits |= (row[t] != 0.f) ? (1u << t) : 0u;
        tileu[xx * 17 + lane] = bits;
      }
    }
    __syncthreads();
    int c2 = tid >> 4, xx2 = tid & 15;
    mp[((size_t)(c2 * NX + y)) * NX + xt * 16 + xx2] = tileu[xx2 * 17 + c2];
  } else {
    int r = bid - 6400;
    int xt = r % 20, y = r / 20;
    int xx = tid >> 4, c = tid & 15;
    float2* tilef = (float2*)shmem;  // [16][17]
    size_t si_ = (size_t)((xt * 16 + xx) * NX + y) * NC + c;
    tilef[xx * 17 + c] = make_float2(kr[si_], ki[si_]);
    __syncthreads();
    int c2 = tid >> 4, xx2 = tid & 15;
    kT[((size_t)(c2 * NX + y)) * NX + xt * 16 + xx2] = tilef[xx2 * 17 + c2];
  }
}

// Pass 1 (fused): bid < NX*G -> x-axis fp16 IFFT writing tmp[cg][t][ky][nx]
// (pre-signed (-1)^nx*(-1)^ky). Extra blocks (first chunk only):
//  [fftN, fftN+6400)        smaps [x][y][c] -> sT[c][x][y] half2 *(-1)^y
//  [fftN+6400, fftN+9600)   flow -> fs[t][nx][ny] float2
//  [fftN+9600, fftN+9800)   zero out_f
// These are BW-bound and overlap with the VALU-bound FFT blocks.
__global__ __launch_bounds__(256) void pass1_k(
    const float2* __restrict__ kT, const unsigned int* __restrict__ mp,
    __half2* __restrict__ tmp, int c0, int G, const float* __restrict__ sr,
    const float* __restrict__ si, const float* __restrict__ fl,
    __half2* __restrict__ sT, float2* __restrict__ fs,
    float* __restrict__ out_f) {
  __shared__ __align__(16) char shmem[6528];
  int bid = blockIdx.x, tid = threadIdx.x;
  int fftN = NX * G;
  if (bid < fftN) {
    int y = bid % NX, cg = bid / NX, c = c0 + cg;
    int lane = tid & 63, w = tid >> 6;
    __half2 v[5];
    unsigned int mb[5];
    size_t rowbase = ((size_t)c * NX + y) * NX;
#pragma unroll
    for (int q = 0; q < 5; ++q) {
      int x = 5 * lane + q;
      float2 kv = kT[rowbase + x];
      float sg = ((lane + q) & 1) ? -INV320 : INV320;  // (-1)^x / 320
      v[q] = __floats2half2_rn(kv.x * sg, kv.y * sg);
      mb[q] = mp[rowbase + x];
    }
    TwH tw;
    make_twh(lane, tw);
    int r6 = rev6(lane);
    float osg = ((lane & 32) ? -1.f : 1.f) * ((y & 1) ? -1.f : 1.f);
    __half2 osg2 = __floats2half2_rn(osg, osg);
    for (int t = w; t < NT; t += 4) {
      __half2 z[5];
#pragma unroll
      for (int q = 0; q < 5; ++q)
        z[q] = u2h(((mb[q] >> t) & 1u) ? h2u(v[q]) : 0u);
      fft320h(z, tw);
      __half2* dst = tmp + ((size_t)(cg * NT + t) * NX + y) * NX;
#pragma unroll
      for (int k2 = 0; k2 < 5; ++k2) dst[r6 + 64 * k2] = __hmul2(osg2, z[k2]);
    }
  } else if (bid < fftN + 6400) {
    int r = bid - fftN;
    int yt = r % 20, x = r / 20;
    int yy = tid >> 4, c = tid & 15;
    float2* tiles = (float2*)shmem;  // [16][17]
    size_t si_ = (size_t)(x * NX + yt * 16 + yy) * NC + c;
    tiles[yy * 17 + c] = make_float2(sr[si_], si[si_]);
    __syncthreads();
    int c2 = tid >> 4, yy2 = tid & 15;
    float2 v = tiles[yy2 * 17 + c2];
    float sg = (yy2 & 1) ? -1.f : 1.f;  // (-1)^ny pre-sign
    sT[((size_t)(c2 * NX + x)) * NX + yt * 16 + yy2] =
        __floats2half2_rn(v.x * sg, v.y * sg);
  } else if (bid < fftN + 9600) {
    int r = bid - fftN - 6400;
    int nyt = r % 10, nx = r / 10;
    float* buf = (float*)shmem;  // [1600]
    size_t base = (size_t)(nx * NX + nyt * 32) * (2 * NT);
    const float2* src2 = (const float2*)(fl + base);  // 8B-aligned
    float2* buf2 = (float2*)shmem;
    for (int f = tid; f < 800; f += 256) buf2[f] = src2[f];
    __syncthreads();
    for (int f = tid; f < 1600; f += 256) {
      int t = f / 64;
      int k = f % 64;
      int nyl = k >> 1, d = k & 1;
      size_t di = ((size_t)(t * NX + nx) * NX + nyt * 32 + nyl) * 2 + d;
      ((float*)fs)[di] = buf[(nyl * 2 + d) * NT + t];
    }
  } else {
    int idx = (bid - fftN - 9600) * 256 + tid;  // 51200 float4
    ((float4*)out_f)[idx] = make_float4(0.f, 0.f, 0.f, 0.f);
  }
}

// Pass 2: y-axis IFFT (fp16-packed) + conj(smaps) f32 MAC -> im_aux fp16.
// 256 threads = 4 waves; block = (nx-tile of 4, t); wave j owns nx.
__global__ __launch_bounds__(256) void pass2_k(
    const __half2* __restrict__ tmp, const __half2* __restrict__ sT,
    __half2* __restrict__ im_aux, int c0, int G, int first) {
  int bx = blockIdx.x, t = blockIdx.y;
  int nxt_ = (bx >> 3) + 10 * (bx & 7);  // bijective on [0,80)
  int tid = threadIdx.x, lane = tid & 63, j = tid >> 6;
  int nx = nxt_ * 4 + j;
  int k1 = rev6(lane);
  TwH tw;
  make_twh(lane, tw);
  __shared__ __half2 tile[2][NX][5];  // 12.8 KB
  v2f acc[5] = {{0, 0}, {0, 0}, {0, 0}, {0, 0}, {0, 0}};

  int off[5], lw[5];
#pragma unroll
  for (int q = 0; q < 5; ++q) {
    int f = tid + q * 256;
    off[q] = (f >> 2) * NX + (f & 3);
    lw[q] = (f >> 2) * 5 + (f & 3);
  }
  const size_t pstride = (size_t)NT * NX * NX;
  const __half2* sbase = tmp + (size_t)t * NX * NX + nxt_ * 4;
  __half2* lds = &tile[0][0][0];

  __half2 nb[5];
#pragma unroll
  for (int q = 0; q < 5; ++q) nb[q] = sbase[off[q]];

  for (int cg = 0; cg < G; ++cg) {
    __half2 cb[5];
#pragma unroll
    for (int q = 0; q < 5; ++q) cb[q] = nb[q];
    if (cg + 1 < G) {
      const __half2* s = sbase + (size_t)(cg + 1) * pstride;
#pragma unroll
      for (int q = 0; q < 5; ++q) nb[q] = s[off[q]];  // in flight across iter
    }
    __half2* buf = lds + (cg & 1) * (NX * 5);
#pragma unroll
    for (int q = 0; q < 5; ++q) buf[lw[q]] = cb[q];
    const __half2* srow = sT + ((size_t)(c0 + cg) * NX + nx) * NX;
    __half2 smh[5];
#pragma unroll
    for (int k2 = 0; k2 < 5; ++k2) smh[k2] = srow[k1 + 64 * k2];
    __syncthreads();
    __half2 z[5];
#pragma unroll
    for (int q = 0; q < 5; ++q) z[q] = buf[(5 * lane + q) * 5 + j];
    fft320h(z, tw);
#pragma unroll
    for (int k2 = 0; k2 < 5; ++k2) {
      float2 sm = __half22float2(smh[k2]);
      float2 zf = __half22float2(z[k2]);
      v2f zv = {zf.x, zf.y};
      v2f zc = {zf.y, -zf.x};  // conj-MAC helper
      acc[k2] += sm.x * zv + sm.y * zc;
    }
  }
  __half2* dst = im_aux + ((size_t)t * NX + nx) * NX;
#pragma unroll
  for (int k2 = 0; k2 < 5; ++k2) {
    int ny = k1 + 64 * k2;
    v2f nv = acc[k2];  // (-1)^ny folded into sT
    if (!first) {
      float2 old = __half22float2(dst[ny]);
      nv.x += old.x;
      nv.y += old.y;
    }
    dst[ny] = __floats2half2_rn(nv.x, nv.y);
  }
}

// Scatter: block (band b, seg, frame t). LDS-privatized 32-row band of
// __half2 (re,im) cells; taps via ds_pk_add_f16 (4 lane-atomics/element).
__global__ __launch_bounds__(1024) void scatter_k(
    const __half2* __restrict__ im, const float2* __restrict__ fs,
    __half2* __restrict__ out_p, float* __restrict__ out_f, int nseg) {
  int b = blockIdx.x, seg = blockIdx.y, t = blockIdx.z;
  int r0 = b * BR;
  int tid = threadIdx.x, lane = tid & 63, w = tid >> 6;
  __shared__ __half2 acc[BR * NX];  // 40 KB
  const __half2 h2z = __floats2half2_rn(0.f, 0.f);
  for (int i = tid; i < BR * NX; i += 1024) acc[i] = h2z;
  __syncthreads();
  int lo = max(r0 - WH, 0), hi = min(r0 + BR + WH, NX);
  int stride = 16 * nseg;
  for (int nx = lo + seg * 16 + w; nx < hi; nx += stride) {
    bool own = (nx >= r0) && (nx < r0 + BR);
    const __half2* imrow = im + ((size_t)t * NX + nx) * NX;
    const float2* frow = fs + ((size_t)t * NX + nx) * NX;
#pragma unroll
    for (int q = 0; q < 5; ++q) {
      int ny = lane + 64 * q;
      float2 v = __half22float2(imrow[ny]);
      float2 fl = frow[ny];
      float px = fminf(fmaxf((float)nx + fl.x, 0.f), 319.f);
      float py = fminf(fmaxf((float)ny + fl.y, 0.f), 319.f);
      int x0 = (int)floorf(px), y0 = (int)floorf(py);
      int x1 = min(x0 + 1, NX - 1), y1 = min(y0 + 1, NX - 1);
      float wx = px - (float)x0, wy = py - (float)y0;
      float w00 = (1.f - wx) * (1.f - wy), w01 = (1.f - wx) * wy;
      float w10 = wx * (1.f - wy), w11 = wx * wy;
#pragma unroll
      for (int half = 0; half < 2; ++half) {
        int r = half ? x1 : x0;
        float wa = half ? w10 : w00;
        float wb = half ? w11 : w01;
        if (r >= r0 && r < r0 + BR) {
          unsafeAtomicAdd(&acc[(r - r0) * NX + y0],
                          __floats2half2_rn(wa * v.x, wa * v.y));
          unsafeAtomicAdd(&acc[(r - r0) * NX + y1],
                          __floats2half2_rn(wb * v.x, wb * v.y));
        } else if (own) {
          int rb = (r / BR) * BR;
          if (nx < rb - WH || nx >= rb + BR + WH) {  // no band reads nx
            unsafeAtomicAdd(&out_f[((size_t)r * NX + y0) * 2], wa * v.x);
            unsafeAtomicAdd(&out_f[((size_t)r * NX + y0) * 2 + 1], wa * v.y);
            unsafeAtomicAdd(&out_f[((size_t)r * NX + y1) * 2], wb * v.x);
            unsafeAtomicAdd(&out_f[((size_t)r * NX + y1) * 2 + 1], wb * v.y);
          }
        }
      }
    }
  }
  __syncthreads();
  __half2* dst = out_p + (size_t)(seg * NT + t) * NX * NX + (size_t)r0 * NX;
  for (int i = tid; i < BR * NX; i += 1024) dst[i] = acc[i];
}

// out = out_f + sum_{seg,t} out_p (half2 slices)
__global__ __launch_bounds__(256) void reduce_k(
    const __half2* __restrict__ out_p, const float* __restrict__ out_f,
    float* __restrict__ out, int nslice) {
  const int n = NX * NX;  // 102400 cells
  int i = blockIdx.x * 256 + threadIdx.x;
  if (i >= n) return;
  float2 s = ((const float2*)out_f)[i];
  for (int k = 0; k < nslice; ++k) {
    float2 v = __half22float2(out_p[(size_t)k * n + i]);
    s.x += v.x;
    s.y += v.y;
  }
  ((float2*)out)[i] = s;
}

extern "C" void kernel_launch(void* const* d_in, const int* in_sizes, int n_in,
                              void* d_out, int out_size, void* d_ws,
                              size_t ws_size, hipStream_t stream) {
  const float* kr = (const float*)d_in[0];
  const float* ki = (const float*)d_in[1];
  const float* mask = (const float*)d_in[2];
  const float* sr = (const float*)d_in[3];
  const float* si = (const float*)d_in[4];
  const float* fl = (const float*)d_in[5];
  float* out = (float*)d_out;

  const size_t tmp1 = (size_t)NT * NX * NX * 4;      // fp16 complex, per coil
  const size_t kT_b = (size_t)NC * NX * NX * 8;
  const size_t sT_b = (size_t)NC * NX * NX * 4;      // half2
  const size_t fs_b = (size_t)NT * NX * NX * 8;
  const size_t mp_b = (size_t)NC * NX * NX * 4;
  const size_t ia_b = (size_t)NT * NX * NX * 4;      // half2
  const size_t of_b = (size_t)NX * NX * 8;
  const size_t op1 = (size_t)NT * NX * NX * 4;       // half2, per segment

  int NSEG = 2, G = 16;
  for (;;) {
    size_t fixed = kT_b + sT_b + fs_b + mp_b + ia_b + of_b + NSEG * op1;
    if (ws_size >= fixed + (size_t)G * tmp1) break;
    if (G > 1) { G >>= 1; continue; }
    if (NSEG > 1) { NSEG >>= 1; G = 16; continue; }
    break;  // minimal config; assume it fits
  }

  char* w = (char*)d_ws;
  __half2* tmp = (__half2*)w;    w += (size_t)G * tmp1;
  float2* kT = (float2*)w;       w += kT_b;
  __half2* sT = (__half2*)w;     w += sT_b;
  float2* fs = (float2*)w;       w += fs_b;
  __half2* im_aux = (__half2*)w; w += ia_b;
  __half2* out_p = (__half2*)w;  w += (size_t)NSEG * op1;
  float* out_f = (float*)w;      w += of_b;
  unsigned int* mp = (unsigned int*)w;

  prep_k<<<12800, 256, 0, stream>>>(mask, kr, ki, mp, kT);

  for (int c0 = 0; c0 < NC; c0 += G) {
    int extra = (c0 == 0) ? 9800 : 0;  // smaps + flow + out_f zero
    pass1_k<<<NX * G + extra, 256, 0, stream>>>(kT, mp, tmp, c0, G, sr, si,
                                                fl, sT, fs, out_f);
    pass2_k<<<dim3(80, NT), 256, 0, stream>>>(tmp, sT, im_aux, c0, G,
                                              c0 == 0 ? 1 : 0);
  }
  scatter_k<<<dim3(NX / BR, NSEG, NT), 1024, 0, stream>>>(im_aux, fs, out_p,
                                                          out_f, NSEG);
  reduce_k<<<400, 256, 0, stream>>>(out_p, out_f, out, NSEG * NT);
}